// Round 2
// baseline (2956.032 us; speedup 1.0000x reference)
//
#include <hip/hip_runtime.h>

#define N_NODES 100000
#define D_FEAT  256
#define N_ATT   256

// ---- types ----
typedef _Float16 f16x4 __attribute__((ext_vector_type(4)));
typedef _Float16 f16x8 __attribute__((ext_vector_type(8)));
typedef float    f32x16 __attribute__((ext_vector_type(16)));

// ---- helpers ----
// fp32 -> f16 RNE (v_cvt_f16_f32, default round mode)
__device__ __forceinline__ unsigned short f16b(float f) {
    _Float16 h = (_Float16)f;
    return __builtin_bit_cast(unsigned short, h);
}

// load a f16x8 fragment as two 8B reads (LDK=36 rows are 8B-aligned only)
__device__ __forceinline__ f16x8 ld8h(const unsigned short* p) {
    f16x4 lo = *(const f16x4*)p;
    f16x4 hi = *(const f16x4*)(p + 4);
    return __builtin_shufflevector(lo, hi, 0, 1, 2, 3, 4, 5, 6, 7);
}

// ============================================================================
// Kernel 1: split-K GEMM  C[v] += W @ x_v
//   R5 (resubmitted R6 unchanged — R5 bench was an infra failure):
//   - f16 single-MFMA (v_mfma_f32_32x32x16_f16). W,x both f16-RNE (2^-11 rel
//     err) is MORE accurate than old bf16(x) * (hi+lo bf16 W) (x was the
//     2^-9 error floor). Halves MFMA count, drops the Al LDS plane
//     (72 -> 54 KB/wg) and the split1 VALU work.
//   - 2-deep x prefetch: pbA/pbB register double-buffer. stage(k) consumes
//     x-loads issued a FULL iteration earlier -> HBM latency (~900cy) is
//     covered by an entire compute+stage+barrier step instead of one
//     compute phase. W stays 1-deep (L3-resident, short latency); issued
//     BEFORE x each iter so the vmcnt wait on pa leaves x in flight.
//   - Register budget: acc 64 + pa 8 + pbA/pbB 32 + misc ~ 124 <= 128
//     -> still 4 waves/SIMD under __launch_bounds__(512, 4).
// ============================================================================
#define LDK 36
#define BUF_SHORTS ((128 + 256) * LDK)   // Ah(128 rows) + Bh(256 rows)

__global__ __launch_bounds__(512, 4) void gemm_split(
    const float* __restrict__ x1, const float* __restrict__ x2,
    const float* __restrict__ x3, const float* __restrict__ W,
    float* __restrict__ C, int chunk)
{
    extern __shared__ unsigned short lds[];

    const int bid = blockIdx.x;
    const int s   = bid / 6;        // split index
    const int pos = bid % 6;
    const int v   = pos >> 1;
    const int m0  = (pos & 1) * 128;
    const float* __restrict__ X = (v == 0) ? x1 : (v == 1) ? x2 : x3;

    const int ks = s * chunk;
    const int ke = min(ks + chunk, N_NODES);   // ke - ks is a multiple of 32

    const int tid  = threadIdx.x;
    const int lane = tid & 63;
    const int wave = tid >> 6;
    const int mstrip = (wave & 3) * 32;    // wave m offset within 128
    const int nhalf  = (wave >> 2) * 128;  // wave n offset within 256

    // staging maps
    const int a_m   = tid >> 3;            // 0..63
    const int a_kk  = (tid & 7) * 4;       // 0..28
    const int b_n64 = tid & 63;
    const int b_nb  = (tid >> 8) * 64;     // 0 or 64
    const int b_kq4 = ((tid >> 6) & 3) * 4;  // wave-uniform k-quad

    const int l31 = lane & 31;
    const int khalf = (lane >> 5) * 8;

    f32x16 acc[4] = {};  // 4 n-blocks of 32x32
    float4 pa[2];
    float  pbA[4][4], pbB[4][4];   // 2-deep x pipeline

    const float* Wb = W + (size_t)(m0 + a_m) * N_NODES + a_kk;

    // per-thread constant x offsets (element units)
    int xoff[4];
    #pragma unroll
    for (int p = 0; p < 4; ++p)
        xoff[p] = ((p & 1) * 16 + b_kq4) * D_FEAT + (p >> 1) * 128 + b_nb + b_n64;

    auto issueW = [&](int kg0) {
        #pragma unroll
        for (int p = 0; p < 2; ++p)
            pa[p] = *(const float4*)(Wb + (size_t)p * 64 * N_NODES + kg0);
    };

    auto issueX = [&](int kg0, float (&pb)[4][4]) {
        const float* xb = X + (size_t)kg0 * D_FEAT;
        #pragma unroll
        for (int p = 0; p < 4; ++p) {
            const float* xp = xb + xoff[p];
            pb[p][0] = xp[0];             // each: 64 consecutive floats across
            pb[p][1] = xp[D_FEAT];        // the wave = one 256 B transaction
            pb[p][2] = xp[2 * D_FEAT];
            pb[p][3] = xp[3 * D_FEAT];
        }
    };

    auto stage = [&](unsigned short* buf, const float (&pb)[4][4]) {
        unsigned short* Ah = buf;
        unsigned short* Bh = buf + 128 * LDK;
        // A first: pa is the NEWEST in-flight load set, so the vmcnt wait
        // here retires pa (and the older pb) while the other x-set stays
        // outstanding.
        #pragma unroll
        for (int p = 0; p < 2; ++p) {
            ushort4 h4;
            h4.x = f16b(pa[p].x); h4.y = f16b(pa[p].y);
            h4.z = f16b(pa[p].z); h4.w = f16b(pa[p].w);
            *(ushort4*)(Ah + (p * 64 + a_m) * LDK + a_kk) = h4;
        }
        #pragma unroll
        for (int p = 0; p < 4; ++p) {
            int n  = (p >> 1) * 128 + b_nb + b_n64;
            int kb = (p & 1) * 16 + b_kq4;
            ushort4 h4;
            h4.x = f16b(pb[p][0]); h4.y = f16b(pb[p][1]);
            h4.z = f16b(pb[p][2]); h4.w = f16b(pb[p][3]);
            *(ushort4*)(Bh + n * LDK + kb) = h4;
        }
    };

    auto compute = [&](const unsigned short* buf) {
        const unsigned short* Ah = buf;
        const unsigned short* Bh = buf + 128 * LDK;
        #pragma unroll
        for (int kk = 0; kk < 2; ++kk) {
            int kf = kk * 16 + khalf;
            f16x8 ah = ld8h(Ah + (mstrip + l31) * LDK + kf);
            #pragma unroll
            for (int nb = 0; nb < 4; ++nb) {
                f16x8 bh = ld8h(Bh + (nhalf + nb * 32 + l31) * LDK + kf);
                acc[nb] = __builtin_amdgcn_mfma_f32_32x32x16_f16(ah, bh, acc[nb], 0, 0, 0);
            }
        }
    };

    // ---- prologue: tile ks into buf0, x(ks+32) already in flight ----
    issueW(ks);
    issueX(ks, pbA);
    issueX(ks + 32, pbB);       // every split has >= 17 tiles, always valid
    stage(lds, pbA);
    __syncthreads();

    // ---- main loop: one barrier per k-step, roles hardcoded (no dynamic
    //      indexing of the pb sets -> everything stays in registers) ----
    int q = 0, k0 = ks;
    while (true) {
        if (k0 + 32 < ke) issueW(k0 + 32);          // W before x: vmcnt order
        if (k0 + 64 < ke) issueX(k0 + 64, pbA);
        compute(lds + q * BUF_SHORTS);
        if (k0 + 32 >= ke) break;
        stage(lds + (q ^ 1) * BUF_SHORTS, pbB);
        __syncthreads(); q ^= 1; k0 += 32;

        if (k0 + 32 < ke) issueW(k0 + 32);
        if (k0 + 64 < ke) issueX(k0 + 64, pbB);
        compute(lds + q * BUF_SHORTS);
        if (k0 + 32 >= ke) break;
        stage(lds + (q ^ 1) * BUF_SHORTS, pbA);
        __syncthreads(); q ^= 1; k0 += 32;
    }

    // ---- epilogue: atomic flush of split-K partials ----
    float* Cv = C + v * (N_ATT * D_FEAT);
    const int col = l31;
    const int rbase = 4 * (lane >> 5);
    #pragma unroll
    for (int nb = 0; nb < 4; ++nb) {
        int gj = nhalf + nb * 32 + col;
        #pragma unroll
        for (int r = 0; r < 16; ++r) {
            int row = (r & 3) + 8 * (r >> 2) + rbase;
            int gi = m0 + mstrip + row;
            unsafeAtomicAdd(Cv + gi * D_FEAT + gj, acc[nb][r]);
        }
    }
}

// ============================================================================
// Kernel 2: scores[v][j] = sum_i h[i] * tanh(C[v][i][j])   (atomic partial)
// ============================================================================
__global__ __launch_bounds__(256) void score_kernel(
    const float* __restrict__ C, const float* __restrict__ h,
    float* __restrict__ scores)
{
    const int v  = blockIdx.x >> 3;
    const int ig = blockIdx.x & 7;
    const int j  = threadIdx.x;
    const float* Cv = C + v * (N_ATT * D_FEAT);
    float s = 0.f;
    #pragma unroll 4
    for (int i = ig * 32; i < ig * 32 + 32; ++i)
        s += h[i] * tanhf(Cv[i * D_FEAT + j]);
    unsafeAtomicAdd(scores + v * D_FEAT + j, s);
}

// ============================================================================
// Kernel 3: out = softmax_v(scores)[v][j] * x_v
//   Column-stationary. Each thread owns 4 columns x 40 rows; softmax
//   (12 transcendentals) computed ONCE per thread, inner loop is pure
//   3-FMA streaming -> copy-roofline regardless of trans-unit behavior.
// ============================================================================
#define OUT_RPB 40   // rows per block -> 2500 blocks

__device__ __forceinline__ void softmax3(float t0, float t1, float t2,
                                         float& w0, float& w1, float& w2) {
    float m = fmaxf(t0, fmaxf(t1, t2));
    float e0 = __expf(t0 - m), e1 = __expf(t1 - m), e2 = __expf(t2 - m);
    float inv = 1.0f / (e0 + e1 + e2);
    w0 = e0 * inv; w1 = e1 * inv; w2 = e2 * inv;
}

__global__ __launch_bounds__(256) void out_kernel(
    const float* __restrict__ x1, const float* __restrict__ x2,
    const float* __restrict__ x3, const float* __restrict__ scores,
    float* __restrict__ out)
{
    const int col = (threadIdx.x & 63) * 4;   // 64 lanes cover all 256 cols
    const int w   = threadIdx.x >> 6;         // wave 0..3

    float4 s0 = *(const float4*)(scores + col);
    float4 s1 = *(const float4*)(scores + D_FEAT + col);
    float4 s2 = *(const float4*)(scores + 2 * D_FEAT + col);
    float4 w0, w1, w2;
    softmax3(s0.x, s1.x, s2.x, w0.x, w1.x, w2.x);
    softmax3(s0.y, s1.y, s2.y, w0.y, w1.y, w2.y);
    softmax3(s0.z, s1.z, s2.z, w0.z, w1.z, w2.z);
    softmax3(s0.w, s1.w, s2.w, w0.w, w1.w, w2.w);

    size_t base0 = (size_t)(blockIdx.x * OUT_RPB + w) * D_FEAT + col;
    #pragma unroll 2
    for (int i = 0; i < OUT_RPB / 4; ++i) {
        size_t base = base0 + (size_t)i * 4 * D_FEAT;
        float4 a = *(const float4*)(x1 + base);
        float4 b = *(const float4*)(x2 + base);
        float4 c = *(const float4*)(x3 + base);
        float4 o;
        o.x = w0.x * a.x + w1.x * b.x + w2.x * c.x;
        o.y = w0.y * a.y + w1.y * b.y + w2.y * c.y;
        o.z = w0.z * a.z + w1.z * b.z + w2.z * c.z;
        o.w = w0.w * a.w + w1.w * b.w + w2.w * c.w;
        *(float4*)(out + base) = o;
    }
}

// ============================================================================
extern "C" void kernel_launch(void* const* d_in, const int* in_sizes, int n_in,
                              void* d_out, int out_size, void* d_ws, size_t ws_size,
                              hipStream_t stream) {
    const float* x1 = (const float*)d_in[0];
    const float* x2 = (const float*)d_in[1];
    const float* x3 = (const float*)d_in[2];
    const float* W  = (const float*)d_in[3];
    const float* h  = (const float*)d_in[4];
    float* out = (float*)d_out;

    float* C      = (float*)d_ws;                 // 3*256*256 fp32 = 768 KB
    float* scores = C + 3 * N_ATT * D_FEAT;       // 3*256 fp32

    hipMemsetAsync(d_ws, 0, (3 * N_ATT * D_FEAT + 3 * D_FEAT) * sizeof(float), stream);

    // split-K GEMM: 85 splits x 6 (view, m-half) positions = 510 wgs (2/CU)
    const int chunk = 1184;  // 37 full 32-k tiles; last split 544 = 17 tiles
    gemm_split<<<dim3(510), dim3(512), 2 * BUF_SHORTS * 2, stream>>>(x1, x2, x3, W, C, chunk);

    score_kernel<<<dim3(24), dim3(256), 0, stream>>>(C, h, scores);

    out_kernel<<<dim3(N_NODES / OUT_RPB), dim3(256), 0, stream>>>(
        x1, x2, x3, scores, out);
}

// Round 3
// 491.378 us; speedup vs baseline: 6.0158x; 6.0158x over previous
//
#include <hip/hip_runtime.h>

#define N_NODES 100000
#define D_FEAT  256
#define N_ATT   256

// ---- types ----
typedef _Float16 f16x4 __attribute__((ext_vector_type(4)));
typedef _Float16 f16x8 __attribute__((ext_vector_type(8)));
typedef float    f32x16 __attribute__((ext_vector_type(16)));

// ---- helpers ----
// fp32 -> f16 RNE (v_cvt_f16_f32, default round mode)
__device__ __forceinline__ unsigned short f16b(float f) {
    _Float16 h = (_Float16)f;
    return __builtin_bit_cast(unsigned short, h);
}

// load a f16x8 fragment as two 8B reads (LDK=36 rows are 8B-aligned only)
__device__ __forceinline__ f16x8 ld8h(const unsigned short* p) {
    f16x4 lo = *(const f16x4*)p;
    f16x4 hi = *(const f16x4*)(p + 4);
    return __builtin_shufflevector(lo, hi, 0, 1, 2, 3, 4, 5, 6, 7);
}

// ============================================================================
// Kernel 1: split-K GEMM  C[v] += W @ x_v
//   R6: fix R5's scratch-spill disaster (WRITE_SIZE 6.6 GB of spill traffic).
//   Root cause: unified VGPR file -> launch_bounds(512,4) = 128 regs TOTAL;
//   acc 64 left only 64 arch VGPRs, 2-deep prefetch needed ~75+.
//   Rebalance: wave tile 32m x 64n (acc = 32) -> 96 arch VGPRs available.
//   Block tile 128m x 128n, 12 positions (3 view x 2 mh x 2 nh) x 42 splits.
//   BOTH W and x prefetch 2-deep in registers (paA/paB, pbA/pbB = 32 regs):
//   stage(k) consumes loads issued a FULL iteration earlier -> ~900cy HBM
//   latency covered by compute+stage+barrier of the intervening step.
//   f16 single-MFMA kept from R5 (absmax improved to 0.0156).
// ============================================================================
#define LDK 36
#define BUF_SHORTS ((128 + 128) * LDK)   // Ah(128 rows) + Bh(128 rows)

__global__ __launch_bounds__(512, 4) void gemm_split(
    const float* __restrict__ x1, const float* __restrict__ x2,
    const float* __restrict__ x3, const float* __restrict__ W,
    float* __restrict__ C, int chunk)
{
    extern __shared__ unsigned short lds[];

    const int bid = blockIdx.x;
    const int s   = bid / 12;       // split index
    const int pos = bid % 12;
    const int v   = pos >> 2;              // view 0..2
    const int m0  = ((pos >> 1) & 1) * 128;
    const int n0  = (pos & 1) * 128;
    const float* __restrict__ X = (v == 0) ? x1 : (v == 1) ? x2 : x3;

    const int ks = s * chunk;
    const int ke = min(ks + chunk, N_NODES);   // ke - ks is a multiple of 32

    const int tid  = threadIdx.x;
    const int lane = tid & 63;
    const int wave = tid >> 6;
    const int mstrip = (wave & 3) * 32;    // wave m offset within 128
    const int nhalf  = (wave >> 2) * 64;   // wave n offset within 128

    // staging maps
    const int a_m   = tid >> 3;            // 0..63 (rows a_m, a_m+64)
    const int a_kk  = (tid & 7) * 4;       // 0..28
    const int b_n   = (tid & 63) + (tid >> 8) * 64;  // 0..127
    const int b_kq4 = ((tid >> 6) & 3) * 4;          // wave-uniform k-quad

    const int l31 = lane & 31;
    const int khalf = (lane >> 5) * 8;

    f32x16 acc[2] = {};            // 2 n-blocks of 32x32
    float4 paA[2], paB[2];         // 2-deep W pipeline (8 regs each)
    float  pbA[2][4], pbB[2][4];   // 2-deep x pipeline (8 regs each)

    const float* Wb = W + (size_t)(m0 + a_m) * N_NODES + a_kk;
    const int xoff0 = b_kq4 * D_FEAT + n0 + b_n;   // element offset in x slab

    auto issueW = [&](int kg0, float4 (&pa)[2]) {
        #pragma unroll
        for (int p = 0; p < 2; ++p)
            pa[p] = *(const float4*)(Wb + (size_t)p * 64 * N_NODES + kg0);
    };

    auto issueX = [&](int kg0, float (&pb)[2][4]) {
        const float* xb = X + (size_t)kg0 * D_FEAT + xoff0;
        #pragma unroll
        for (int p = 0; p < 2; ++p) {
            const float* xp = xb + p * 16 * D_FEAT;
            pb[p][0] = xp[0];             // 64 consecutive floats across the
            pb[p][1] = xp[D_FEAT];        // wave = one 256 B transaction
            pb[p][2] = xp[2 * D_FEAT];
            pb[p][3] = xp[3 * D_FEAT];
        }
    };

    auto stage = [&](unsigned short* buf, const float4 (&pa)[2],
                     const float (&pb)[2][4]) {
        unsigned short* Ah = buf;
        unsigned short* Bh = buf + 128 * LDK;
        #pragma unroll
        for (int p = 0; p < 2; ++p) {
            ushort4 h4;
            h4.x = f16b(pa[p].x); h4.y = f16b(pa[p].y);
            h4.z = f16b(pa[p].z); h4.w = f16b(pa[p].w);
            *(ushort4*)(Ah + (p * 64 + a_m) * LDK + a_kk) = h4;
        }
        #pragma unroll
        for (int p = 0; p < 2; ++p) {
            int kb = p * 16 + b_kq4;
            ushort4 h4;
            h4.x = f16b(pb[p][0]); h4.y = f16b(pb[p][1]);
            h4.z = f16b(pb[p][2]); h4.w = f16b(pb[p][3]);
            *(ushort4*)(Bh + b_n * LDK + kb) = h4;
        }
    };

    auto compute = [&](const unsigned short* buf) {
        const unsigned short* Ah = buf;
        const unsigned short* Bh = buf + 128 * LDK;
        #pragma unroll
        for (int kk = 0; kk < 2; ++kk) {
            int kf = kk * 16 + khalf;
            f16x8 ah = ld8h(Ah + (mstrip + l31) * LDK + kf);
            #pragma unroll
            for (int nb = 0; nb < 2; ++nb) {
                f16x8 bh = ld8h(Bh + (nhalf + nb * 32 + l31) * LDK + kf);
                acc[nb] = __builtin_amdgcn_mfma_f32_32x32x16_f16(ah, bh, acc[nb], 0, 0, 0);
            }
        }
    };

    // ---- prologue: both deep-sets filled; tile ks staged into buf0 ----
    issueW(ks, paA);      issueX(ks, pbA);
    issueW(ks + 32, paB); issueX(ks + 32, pbB);   // every split >= 50 tiles
    stage(lds, paA, pbA);
    __syncthreads();

    // ---- main loop: one barrier per k-step; roles hardcoded so every
    //      prefetch buffer is statically indexed (stays in registers) ----
    int q = 0, k0 = ks;
    while (true) {
        if (k0 + 64 < ke) { issueW(k0 + 64, paA); issueX(k0 + 64, pbA); }
        compute(lds + q * BUF_SHORTS);
        if (k0 + 32 >= ke) break;
        stage(lds + (q ^ 1) * BUF_SHORTS, paB, pbB);
        __syncthreads(); q ^= 1; k0 += 32;

        if (k0 + 64 < ke) { issueW(k0 + 64, paB); issueX(k0 + 64, pbB); }
        compute(lds + q * BUF_SHORTS);
        if (k0 + 32 >= ke) break;
        stage(lds + (q ^ 1) * BUF_SHORTS, paA, pbA);
        __syncthreads(); q ^= 1; k0 += 32;
    }

    // ---- epilogue: atomic flush of split-K partials ----
    float* Cv = C + v * (N_ATT * D_FEAT);
    const int col = l31;
    const int rbase = 4 * (lane >> 5);
    #pragma unroll
    for (int nb = 0; nb < 2; ++nb) {
        int gj = n0 + nhalf + nb * 32 + col;
        #pragma unroll
        for (int r = 0; r < 16; ++r) {
            int row = (r & 3) + 8 * (r >> 2) + rbase;
            int gi = m0 + mstrip + row;
            unsafeAtomicAdd(Cv + gi * D_FEAT + gj, acc[nb][r]);
        }
    }
}

// ============================================================================
// Kernel 2: scores[v][j] = sum_i h[i] * tanh(C[v][i][j])   (atomic partial)
// ============================================================================
__global__ __launch_bounds__(256) void score_kernel(
    const float* __restrict__ C, const float* __restrict__ h,
    float* __restrict__ scores)
{
    const int v  = blockIdx.x >> 3;
    const int ig = blockIdx.x & 7;
    const int j  = threadIdx.x;
    const float* Cv = C + v * (N_ATT * D_FEAT);
    float s = 0.f;
    #pragma unroll 4
    for (int i = ig * 32; i < ig * 32 + 32; ++i)
        s += h[i] * tanhf(Cv[i * D_FEAT + j]);
    unsafeAtomicAdd(scores + v * D_FEAT + j, s);
}

// ============================================================================
// Kernel 3: out = softmax_v(scores)[v][j] * x_v
//   Column-stationary: softmax computed once per thread (4 cols), inner
//   loop is pure 3-FMA streaming at the copy roofline.
// ============================================================================
#define OUT_RPB 40   // rows per block -> 2500 blocks

__device__ __forceinline__ void softmax3(float t0, float t1, float t2,
                                         float& w0, float& w1, float& w2) {
    float m = fmaxf(t0, fmaxf(t1, t2));
    float e0 = __expf(t0 - m), e1 = __expf(t1 - m), e2 = __expf(t2 - m);
    float inv = 1.0f / (e0 + e1 + e2);
    w0 = e0 * inv; w1 = e1 * inv; w2 = e2 * inv;
}

__global__ __launch_bounds__(256) void out_kernel(
    const float* __restrict__ x1, const float* __restrict__ x2,
    const float* __restrict__ x3, const float* __restrict__ scores,
    float* __restrict__ out)
{
    const int col = (threadIdx.x & 63) * 4;   // 64 lanes cover all 256 cols
    const int w   = threadIdx.x >> 6;         // wave 0..3

    float4 s0 = *(const float4*)(scores + col);
    float4 s1 = *(const float4*)(scores + D_FEAT + col);
    float4 s2 = *(const float4*)(scores + 2 * D_FEAT + col);
    float4 w0, w1, w2;
    softmax3(s0.x, s1.x, s2.x, w0.x, w1.x, w2.x);
    softmax3(s0.y, s1.y, s2.y, w0.y, w1.y, w2.y);
    softmax3(s0.z, s1.z, s2.z, w0.z, w1.z, w2.z);
    softmax3(s0.w, s1.w, s2.w, w0.w, w1.w, w2.w);

    size_t base0 = (size_t)(blockIdx.x * OUT_RPB + w) * D_FEAT + col;
    #pragma unroll 2
    for (int i = 0; i < OUT_RPB / 4; ++i) {
        size_t base = base0 + (size_t)i * 4 * D_FEAT;
        float4 a = *(const float4*)(x1 + base);
        float4 b = *(const float4*)(x2 + base);
        float4 c = *(const float4*)(x3 + base);
        float4 o;
        o.x = w0.x * a.x + w1.x * b.x + w2.x * c.x;
        o.y = w0.y * a.y + w1.y * b.y + w2.y * c.y;
        o.z = w0.z * a.z + w1.z * b.z + w2.z * c.z;
        o.w = w0.w * a.w + w1.w * b.w + w2.w * c.w;
        *(float4*)(out + base) = o;
    }
}

// ============================================================================
extern "C" void kernel_launch(void* const* d_in, const int* in_sizes, int n_in,
                              void* d_out, int out_size, void* d_ws, size_t ws_size,
                              hipStream_t stream) {
    const float* x1 = (const float*)d_in[0];
    const float* x2 = (const float*)d_in[1];
    const float* x3 = (const float*)d_in[2];
    const float* W  = (const float*)d_in[3];
    const float* h  = (const float*)d_in[4];
    float* out = (float*)d_out;

    float* C      = (float*)d_ws;                 // 3*256*256 fp32 = 768 KB
    float* scores = C + 3 * N_ATT * D_FEAT;       // 3*256 fp32

    hipMemsetAsync(d_ws, 0, (3 * N_ATT * D_FEAT + 3 * D_FEAT) * sizeof(float), stream);

    // split-K GEMM: 42 splits x 12 (view, m-half, n-half) = 504 wgs (~2/CU)
    const int chunk = 2400;  // 75 full 32-k tiles; last split 1600 = 50 tiles
    gemm_split<<<dim3(504), dim3(512), 2 * BUF_SHORTS * 2, stream>>>(x1, x2, x3, W, C, chunk);

    score_kernel<<<dim3(24), dim3(256), 0, stream>>>(C, h, scores);

    out_kernel<<<dim3(N_NODES / OUT_RPB), dim3(256), 0, stream>>>(
        x1, x2, x3, scores, out);
}